// Round 9
// baseline (885.673 us; speedup 1.0000x reference)
//
#include <hip/hip_runtime.h>
#include <hip/hip_bf16.h>

// Problem constants (B, D, DOUT from reference)
#define BDIM 8192
#define DDIM 4096
#define DOUTD 4096

typedef __attribute__((ext_vector_type(8))) short short8;
typedef __attribute__((ext_vector_type(16))) float floatx16;

// round-to-nearest-even fp32 -> bf16 (bit pattern)
__device__ inline unsigned short f32_to_bf16_rne(float f) {
    unsigned int u = __float_as_uint(f);
    unsigned int lsb = (u >> 16) & 1u;
    u += 0x7fffu + lsb;
    return (unsigned short)(u >> 16);
}

// async global->LDS, 16B per lane; lds base must be wave-uniform
__device__ inline void gload_lds16(const void* g, void* lds) {
    __builtin_amdgcn_global_load_lds(
        (const __attribute__((address_space(1))) void*)g,
        (__attribute__((address_space(3))) void*)lds,
        16, 0, 0);
}

// Convert x (fp32 [B,D]) to bf16 natural (xb [B,D]) and transposed (xT [D,B]).
// v9: LDS tile in [b][d] layout with +2 pad (tile[64][66]) -- both phases
// bank-verified to the wave64 2-lane/bank minimum (old [d][b]+8pad version
// had an 8-way conflict on every scalar store: 144B row stride -> banks
// {0,16} for 16 lanes).
//  Phase A store (ushort2 x2): bank = (33*row + 2j)%32, rows 0-3 cover
//    evens x2 / odds x2 -> free. Phase B read (scalar): bank =
//    (4j + (r>>1))%32, r-pairs share a 4B word (broadcast) -> 2-way, free.
__global__ __launch_bounds__(256)
void convert_transpose_x(const float* __restrict__ x,
                         unsigned short* __restrict__ xb,
                         unsigned short* __restrict__ xT) {
    __shared__ __align__(8) unsigned short tile[64][66];  // [b][d], +2 pad
    const int t = threadIdx.x;
    const int tb = blockIdx.x * 64;   // b offset
    const int td = blockIdx.y * 64;   // d offset
#pragma unroll
    for (int p = 0; p < 4; ++p) {
        int c = t + p * 256;            // [0,1024)
        int row  = c >> 4;              // b-local
        int col4 = (c & 15) << 2;       // d-local
        float4 v = *(const float4*)&x[(size_t)(tb + row) * DDIM + td + col4];
        ushort4 o;
        o.x = f32_to_bf16_rne(v.x);
        o.y = f32_to_bf16_rne(v.y);
        o.z = f32_to_bf16_rne(v.z);
        o.w = f32_to_bf16_rne(v.w);
        *(ushort4*)&xb[(size_t)(tb + row) * DDIM + td + col4] = o;
        ushort2 lo; lo.x = o.x; lo.y = o.y;
        ushort2 hi2; hi2.x = o.z; hi2.y = o.w;
        *(ushort2*)&tile[row][col4]     = lo;   // 4B-aligned: (66*row+col4)*2 % 4 == 0
        *(ushort2*)&tile[row][col4 + 2] = hi2;
    }
    __syncthreads();
#pragma unroll
    for (int p = 0; p < 4; ++p) {
        int c = t + p * 256;
        int drow = c >> 4;              // d-local
        int b4   = (c & 15) << 2;       // b-local
        ushort4 o;
        o.x = tile[b4 + 0][drow];
        o.y = tile[b4 + 1][drow];
        o.z = tile[b4 + 2][drow];
        o.w = tile[b4 + 3][drow];
        *(ushort4*)&xT[(size_t)(td + drow) * BDIM + tb + b4] = o;
    }
}

// Elementwise fp32 -> bf16 for W (v9: 8 elems/thread, 16B writes per G13)
__global__ __launch_bounds__(256)
void convert_w_kernel(const float* __restrict__ W, unsigned short* __restrict__ Wb) {
    size_t i = ((size_t)blockIdx.x * 256 + threadIdx.x) * 8;
    float4 a = *(const float4*)&W[i];
    float4 b = *(const float4*)&W[i + 4];
    short8 o;
    o[0] = (short)f32_to_bf16_rne(a.x);
    o[1] = (short)f32_to_bf16_rne(a.y);
    o[2] = (short)f32_to_bf16_rne(a.z);
    o[3] = (short)f32_to_bf16_rne(a.w);
    o[4] = (short)f32_to_bf16_rne(b.x);
    o[5] = (short)f32_to_bf16_rne(b.y);
    o[6] = (short)f32_to_bf16_rne(b.z);
    o[7] = (short)f32_to_bf16_rne(b.w);
    *(short8*)&Wb[i] = o;
}

// compiler memory fence (zero instructions) + raw barrier
#define CFENCE() asm volatile("" ::: "memory")
#define BAR() do { CFENCE(); __builtin_amdgcn_s_barrier(); CFENCE(); } while (0)
#define MFMA_BF16 __builtin_amdgcn_mfma_f32_32x32x16_bf16

// ---------------------------------------------------------------------------
// GEMM: byte-identical to round-8 v8 (verified passing, 857us total).
// C[m,n] = sum_k A[m,k]*B[n,k]  (+ bias[n]  or  + eps on diagonal)
// 256x256 tile, BK=64, 512 threads = 8 waves (2M x 4N), wave tile 128x64.
// Phases of 4 independent chains of length 2; reads 6/8/4/6 per phase;
// stage Bh1(j+1)|Bh0(j+2)|Ah0(j+2)|Ah1(j+2) at P1..P4; vmcnt(6) at P4 entry
// (vmcnt(0) at j==NT-2); early reads for next tile at end of P4 (post-MFMA,
// post-drain-BAR). LDS [region(2)x16KB][row(256)x64B][p(4)x16B chunks],
// chunk p = c2 ^ ((row>>2)&3) (zero-conflict, measured).
// ---------------------------------------------------------------------------
template <bool HESS>
__global__ __launch_bounds__(512, 2)
void gemm256(const unsigned short* __restrict__ A,
             const unsigned short* __restrict__ B,
             const float* __restrict__ bias,
             float* __restrict__ C,
             int M, int N, int K) {
    __shared__ __align__(16) unsigned short As[32768];  // 2 buf x 2 region x 256 x 32
    __shared__ __align__(16) unsigned short Bs[32768];

    const int t    = threadIdx.x;
    const int lane = t & 63;
    const int w    = t >> 6;          // wave 0..7
    const int lm   = lane & 31;
    const int hi   = lane >> 5;       // k-half within MFMA operand
    const int key2 = (lm >> 2) & 3;   // read-side swizzle key (rows 32-aligned)
    const int wm   = w >> 2;          // 0..1  (M half of block tile)
    const int wn   = w & 3;           // 0..3  (N quarter)
    const size_t bm = (size_t)blockIdx.y * 256;
    const size_t bn = (size_t)blockIdx.x * 256;
    const int NT = K >> 6;            // K-tiles (even: 64 or 128 here)

    // ---- staging source pointers (per lane), inverse-swizzled k chunk ----
    const int kh_w = w >> 2;          // which 64B k-half this wave stages
    const int wq   = w & 3;           // 2KB stripe within (half-tile, region)
    const int rsub = lane >> 2;       // row within 16-row stripe
    const int csrc = (lane & 3) ^ ((lane >> 4) & 3);  // global k-chunk (of 4)
    const unsigned short* gA0 = A + (bm + wq * 32 + rsub) * (size_t)K + kh_w * 32 + csrc * 8;
    const unsigned short* gB0 = B + (bn + wq * 32 + rsub) * (size_t)K + kh_w * 32 + csrc * 8;
    char* ldsA = (char*)As + kh_w * 16384 + wq * 2048;  // + buf*32768 + h*8192
    char* ldsB = (char*)Bs + kh_w * 16384 + wq * 2048;
    const size_t rowK16 = (size_t)16 * K;   // 16 rows (shorts)
    const size_t halfK  = (size_t)128 * K;  // half-tile row jump (shorts)

#define STAGE_A(tj, h, buf) do {                                   \
        const size_t _ko = (size_t)(tj) * 64 + (size_t)(h) * halfK;\
        char* _d = ldsA + (buf) * 32768 + (h) * 8192;              \
        gload_lds16(gA0 + _ko, _d);                                \
        gload_lds16(gA0 + _ko + rowK16, _d + 1024);                \
    } while (0)
#define STAGE_B(tj, h, buf) do {                                   \
        const size_t _ko = (size_t)(tj) * 64 + (size_t)(h) * halfK;\
        char* _d = ldsB + (buf) * 32768 + (h) * 8192;              \
        gload_lds16(gB0 + _ko, _d);                                \
        gload_lds16(gB0 + _ko + rowK16, _d + 1024);                \
    } while (0)

    // ---- read offsets (shorts): addr = AB + ROWb + quad-offset + pos[s] ----
    const int AROWb = (wm * 128 + lm) * 32;  // + mi*1024 (af0) / +2048+mi*1024 (af1)
    const int BROWb = (wn * 32 + lm) * 32;   // + qn*4096
    int pos[4];
#pragma unroll
    for (int s = 0; s < 4; ++s)
        pos[s] = (s >> 1) * 8192 + ((((s & 1) * 2 + hi) ^ key2) * 8);

    floatx16 acc[4][2];   // [m-tile][qn]
#pragma unroll
    for (int i = 0; i < 4; ++i)
#pragma unroll
        for (int j = 0; j < 2; ++j)
#pragma unroll
            for (int g = 0; g < 16; ++g)
                acc[i][j][g] = 0.f;

    short8 af0[2][4], af1[2][4], bf[2][4];   // [mi][s] / [qn][s]

    // early reads (next tile, from AB2): af0[mi][s01] + bf[0][s01]
#define READS_EARLY(AB2) do {                                              \
        _Pragma("unroll")                                                  \
        for (int mi = 0; mi < 2; ++mi) {                                   \
            af0[mi][0] = *(const short8*)&As[(AB2) + AROWb + mi * 1024 + pos[0]]; \
            af0[mi][1] = *(const short8*)&As[(AB2) + AROWb + mi * 1024 + pos[1]]; \
        }                                                                  \
        bf[0][0] = *(const short8*)&Bs[(AB2) + BROWb + pos[0]];            \
        bf[0][1] = *(const short8*)&Bs[(AB2) + BROWb + pos[1]];            \
    } while (0)

#define TILE_BODY(J, BUFC) do {                                            \
        constexpr int AB  = (BUFC) * 16384;                                \
        constexpr int AB2 = ((BUFC) ^ 1) * 16384;                          \
        /* -- P1: read af0 s23 + bf[1] s01; stage Bh1(J+1)->buf^1;      */ \
        /*    MFMA accs{0,1}x{0,1} s=0,1                                */ \
        _Pragma("unroll")                                                  \
        for (int mi = 0; mi < 2; ++mi) {                                   \
            af0[mi][2] = *(const short8*)&As[AB + AROWb + mi * 1024 + pos[2]]; \
            af0[mi][3] = *(const short8*)&As[AB + AROWb + mi * 1024 + pos[3]]; \
        }                                                                  \
        bf[1][0] = *(const short8*)&Bs[AB + BROWb + 4096 + pos[0]];        \
        bf[1][1] = *(const short8*)&Bs[AB + BROWb + 4096 + pos[1]];        \
        if ((J) + 1 < NT) STAGE_B((J) + 1, 1, (BUFC) ^ 1);                 \
        BAR();                                                             \
        __builtin_amdgcn_s_setprio(1);                                     \
        _Pragma("unroll")                                                  \
        for (int s = 0; s < 2; ++s) {                                      \
            acc[0][0] = MFMA_BF16(af0[0][s], bf[0][s], acc[0][0], 0, 0, 0);\
            acc[1][0] = MFMA_BF16(af0[1][s], bf[0][s], acc[1][0], 0, 0, 0);\
            acc[0][1] = MFMA_BF16(af0[0][s], bf[1][s], acc[0][1], 0, 0, 0);\
            acc[1][1] = MFMA_BF16(af0[1][s], bf[1][s], acc[1][1], 0, 0, 0);\
        }                                                                  \
        __builtin_amdgcn_s_setprio(0);                                     \
        asm volatile("s_waitcnt lgkmcnt(0)" ::: "memory");                 \
        BAR();                                                             \
        /* -- P2: read bf s23 (both qn) + af1 s01; stage Bh0(J+2)->buf; */ \
        /*    MFMA accs{0,1}x{0,1} s=2,3                                */ \
        bf[0][2] = *(const short8*)&Bs[AB + BROWb + pos[2]];               \
        bf[0][3] = *(const short8*)&Bs[AB + BROWb + pos[3]];               \
        bf[1][2] = *(const short8*)&Bs[AB + BROWb + 4096 + pos[2]];        \
        bf[1][3] = *(const short8*)&Bs[AB + BROWb + 4096 + pos[3]];        \
        _Pragma("unroll")                                                  \
        for (int mi = 0; mi < 2; ++mi) {                                   \
            af1[mi][0] = *(const short8*)&As[AB + AROWb + 2048 + mi * 1024 + pos[0]]; \
            af1[mi][1] = *(const short8*)&As[AB + AROWb + 2048 + mi * 1024 + pos[1]]; \
        }                                                                  \
        if ((J) + 2 < NT) STAGE_B((J) + 2, 0, (BUFC));                     \
        BAR();                                                             \
        __builtin_amdgcn_s_setprio(1);                                     \
        _Pragma("unroll")                                                  \
        for (int s = 2; s < 4; ++s) {                                      \
            acc[0][0] = MFMA_BF16(af0[0][s], bf[0][s], acc[0][0], 0, 0, 0);\
            acc[1][0] = MFMA_BF16(af0[1][s], bf[0][s], acc[1][0], 0, 0, 0);\
            acc[0][1] = MFMA_BF16(af0[0][s], bf[1][s], acc[0][1], 0, 0, 0);\
            acc[1][1] = MFMA_BF16(af0[1][s], bf[1][s], acc[1][1], 0, 0, 0);\
        }                                                                  \
        __builtin_amdgcn_s_setprio(0);                                     \
        asm volatile("s_waitcnt lgkmcnt(0)" ::: "memory");                 \
        BAR();                                                             \
        /* -- P3: read af1 s23; stage Ah0(J+2)->buf;                    */ \
        /*    MFMA accs{2,3}x{0,1} s=0,1                                */ \
        _Pragma("unroll")                                                  \
        for (int mi = 0; mi < 2; ++mi) {                                   \
            af1[mi][2] = *(const short8*)&As[AB + AROWb + 2048 + mi * 1024 + pos[2]]; \
            af1[mi][3] = *(const short8*)&As[AB + AROWb + 2048 + mi * 1024 + pos[3]]; \
        }                                                                  \
        if ((J) + 2 < NT) STAGE_A((J) + 2, 0, (BUFC));                     \
        BAR();                                                             \
        __builtin_amdgcn_s_setprio(1);                                     \
        _Pragma("unroll")                                                  \
        for (int s = 0; s < 2; ++s) {                                      \
            acc[2][0] = MFMA_BF16(af1[0][s], bf[0][s], acc[2][0], 0, 0, 0);\
            acc[3][0] = MFMA_BF16(af1[1][s], bf[0][s], acc[3][0], 0, 0, 0);\
            acc[2][1] = MFMA_BF16(af1[0][s], bf[1][s], acc[2][1], 0, 0, 0);\
            acc[3][1] = MFMA_BF16(af1[1][s], bf[1][s], acc[3][1], 0, 0, 0);\
        }                                                                  \
        __builtin_amdgcn_s_setprio(0);                                     \
        asm volatile("s_waitcnt lgkmcnt(0)" ::: "memory");                 \
        BAR();                                                             \
        /* -- P4: stage Ah1(J+2)->buf; vmcnt drain; BAR;                */ \
        /*    MFMA accs{2,3}x{0,1} s=2,3; THEN early reads (buf^1)      */ \
        if ((J) + 2 < NT) STAGE_A((J) + 2, 1, (BUFC));                     \
        if ((J) < NT - 2)       asm volatile("s_waitcnt vmcnt(6)" ::: "memory"); \
        else if ((J) == NT - 2) asm volatile("s_waitcnt vmcnt(0)" ::: "memory"); \
        BAR();                                                             \
        __builtin_amdgcn_s_setprio(1);                                     \
        _Pragma("unroll")                                                  \
        for (int s = 2; s < 4; ++s) {                                      \
            acc[2][0] = MFMA_BF16(af1[0][s], bf[0][s], acc[2][0], 0, 0, 0);\
            acc[3][0] = MFMA_BF16(af1[1][s], bf[0][s], acc[3][0], 0, 0, 0);\
            acc[2][1] = MFMA_BF16(af1[0][s], bf[1][s], acc[2][1], 0, 0, 0);\
            acc[3][1] = MFMA_BF16(af1[1][s], bf[1][s], acc[3][1], 0, 0, 0);\
        }                                                                  \
        __builtin_amdgcn_s_setprio(0);                                     \
        if ((J) + 1 < NT) READS_EARLY(AB2);                                \
        BAR();                                                             \
    } while (0)

    // ---- prologue: tile0 full + tile1 {Bh0,Ah0,Ah1}; drain tile0 ----
    STAGE_B(0, 0, 0); STAGE_A(0, 0, 0); STAGE_B(0, 1, 0); STAGE_A(0, 1, 0);
    STAGE_B(1, 0, 1); STAGE_A(1, 0, 1); STAGE_A(1, 1, 1);
    asm volatile("s_waitcnt vmcnt(6)" ::: "memory");
    BAR();
    READS_EARLY(0);   // tile0: af0 s01 + bf[0] s01 from buf0 (post-BAR: safe)

    for (int jj = 0; jj < NT; jj += 2) {
        TILE_BODY(jj, 0);
        TILE_BODY(jj + 1, 1);
    }
#undef STAGE_A
#undef STAGE_B
#undef READS_EARLY
#undef TILE_BODY

    // ---- epilogue: D layout col = lane&31 (n), row = (reg&3)+8*(reg>>2)+4*hi
    float bv[2];
#pragma unroll
    for (int n2 = 0; n2 < 2; ++n2)
        bv[n2] = HESS ? 0.f : bias[bn + n2 * 128 + wn * 32 + lm];
#pragma unroll
    for (int m4 = 0; m4 < 4; ++m4) {
        const size_t mbase = bm + wm * 128 + m4 * 32 + 4 * hi;
#pragma unroll
        for (int n2 = 0; n2 < 2; ++n2) {
            const size_t n = bn + n2 * 128 + wn * 32 + lm;
#pragma unroll
            for (int reg = 0; reg < 16; ++reg) {
                const size_t m = mbase + (reg & 3) + 8 * (reg >> 2);
                float v = acc[m4][n2][reg] + bv[n2];
                if (HESS && m == n) v += 1e-4f;
                C[m * N + n] = v;
            }
        }
    }
}

extern "C" void kernel_launch(void* const* d_in, const int* in_sizes, int n_in,
                              void* d_out, int out_size, void* d_ws, size_t ws_size,
                              hipStream_t stream) {
    const float* x = (const float*)d_in[0];   // [8192, 4096]
    const float* W = (const float*)d_in[1];   // [4096, 4096]
    const float* b = (const float*)d_in[2];   // [4096]

    float* out  = (float*)d_out;                       // [8192, 4096]
    float* hess = out + (size_t)BDIM * DOUTD;          // [4096, 4096]

    // workspace layout (bf16): xb [B,D] | xT [D,B] | Wb [DOUT,D]  = 168 MB
    unsigned short* xb = (unsigned short*)d_ws;
    unsigned short* xT = xb + (size_t)BDIM * DDIM;
    unsigned short* Wb = xT + (size_t)BDIM * DDIM;

    convert_transpose_x<<<dim3(BDIM / 64, DDIM / 64), 256, 0, stream>>>(x, xb, xT);
    convert_w_kernel<<<((size_t)DOUTD * DDIM) / 2048, 256, 0, stream>>>(W, Wb);

    // out = x @ W.T + b : M=8192, N=4096, K=4096  (grid 16 x 32 = 512 blocks)
    gemm256<false><<<dim3(DOUTD / 256, BDIM / 256), 512, 0, stream>>>(
        xb, Wb, b, out, BDIM, DOUTD, DDIM);
    // hess = xT @ xT.T + eps*I : M=N=4096, K=8192  (grid 16 x 16 = 256 blocks)
    gemm256<true><<<dim3(DDIM / 256, DDIM / 256), 512, 0, stream>>>(
        xT, xT, nullptr, hess, DDIM, DDIM, BDIM);
}